// Round 5
// baseline (72090.381 us; speedup 1.0000x reference)
//
#include <hip/hip_runtime.h>
#include <math.h>

#define T_STEPS 8192
#define HID 2048
#define H3 6144
#define NBLK 256
#define CHUNK 2048

typedef float f32x4 __attribute__((ext_vector_type(4)));

// ---------------------------------------------------------------------------
// Coherent access helpers. sc0 sc1 = Infinity-Cache coherence point (cross-
// XCD). sc0 only = L1-bypass, XCD-local L2 coherence (leader->follower relay).
// R5/R6/R8 falsified: end-barrier (+60%), centralized flags (+580%), and
// split-issue pipelined polls (register-lifetime corruption; and net-zero by
// drain arithmetic). Load+waitcnt MUST stay fused in one asm statement.
// ---------------------------------------------------------------------------
__device__ __forceinline__ float4 cload_f4(const float* p) {
    float4 r;
    asm volatile("global_load_dwordx4 %0, %1, off sc0 sc1\n\t"
                 "s_waitcnt vmcnt(0)"
                 : "=&v"(r) : "v"(p) : "memory");
    return r;
}
__device__ __forceinline__ float4 cload_f4_l(const float* p) {   // L2-local
    float4 r;
    asm volatile("global_load_dwordx4 %0, %1, off sc0\n\t"
                 "s_waitcnt vmcnt(0)"
                 : "=&v"(r) : "v"(p) : "memory");
    return r;
}
__device__ __forceinline__ void cstore_f4(float4* p, float x, float y,
                                          float z, float w) {
    f32x4 v; v[0] = x; v[1] = y; v[2] = z; v[3] = w;
    asm volatile("global_store_dwordx4 %0, %1, off sc0 sc1"
                 :: "v"(p), "v"(v) : "memory");
}
__device__ __forceinline__ void cstore_f4_l(float4* p, float x, float y,
                                            float z, float w) {  // L2-local
    f32x4 v; v[0] = x; v[1] = y; v[2] = z; v[3] = w;
    asm volatile("global_store_dwordx4 %0, %1, off sc0"
                 :: "v"(p), "v"(v) : "memory");
}

// LDS-only barrier: __syncthreads() drains vmcnt too; these barriers only
// order LDS traffic -> drain lgkmcnt only, leave vmem acks in flight.
#define BAR_LDS() asm volatile("s_waitcnt lgkmcnt(0)\n\ts_barrier" ::: "memory")

// ---------------------------------------------------------------------------
// Fast gates: v_exp_f32 (2^x) based sigmoid/tanh (R7, validated: -6%).
// ---------------------------------------------------------------------------
__device__ __forceinline__ float fexp2(float x) {
    return __builtin_amdgcn_exp2f(x);
}
__device__ __forceinline__ float frcp(float x) { return __builtin_amdgcn_rcpf(x); }
__device__ __forceinline__ float fsigmoid(float x) {
    return frcp(1.f + fexp2(-1.44269504089f * x));
}
__device__ __forceinline__ float ftanh_(float x) {
    return 2.f * frcp(1.f + fexp2(-2.88539008178f * x)) - 1.f;
}

// ---------------------------------------------------------------------------
// fp32 GEMM: C[M,N] = A[M,K] @ B[N,K]^T + bias, optional ReLU.
// ---------------------------------------------------------------------------
template<int RELU>
__global__ __launch_bounds__(256) void sgemm_bias(
    const float* __restrict__ A, const float* __restrict__ B,
    const float* __restrict__ bias, float* __restrict__ C,
    int M, int N, int K)
{
    __shared__ float As[16][64];
    __shared__ float Bs[16][64];
    const int tid = threadIdx.x;
    const int tm = tid & 15;
    const int tn = tid >> 4;
    const int m0 = blockIdx.y * 64;
    const int n0 = blockIdx.x * 64;
    const int lm = tid >> 2;
    const int lk = (tid & 3) * 4;

    float c[4][4] = {};

    for (int k0 = 0; k0 < K; k0 += 16) {
        float4 av = *(const float4*)(A + (size_t)(m0 + lm) * K + k0 + lk);
        float4 bv = make_float4(0.f, 0.f, 0.f, 0.f);
        const int bn = n0 + lm;
        if (bn < N) bv = *(const float4*)(B + (size_t)bn * K + k0 + lk);
        __syncthreads();
        As[lk+0][lm] = av.x; As[lk+1][lm] = av.y; As[lk+2][lm] = av.z; As[lk+3][lm] = av.w;
        Bs[lk+0][lm] = bv.x; Bs[lk+1][lm] = bv.y; Bs[lk+2][lm] = bv.z; Bs[lk+3][lm] = bv.w;
        __syncthreads();
        #pragma unroll
        for (int kk = 0; kk < 16; kk++) {
            float4 a4 = *(const float4*)&As[kk][tm * 4];
            float4 b4 = *(const float4*)&Bs[kk][tn * 4];
            c[0][0] += a4.x * b4.x; c[0][1] += a4.x * b4.y; c[0][2] += a4.x * b4.z; c[0][3] += a4.x * b4.w;
            c[1][0] += a4.y * b4.x; c[1][1] += a4.y * b4.y; c[1][2] += a4.y * b4.z; c[1][3] += a4.y * b4.w;
            c[2][0] += a4.z * b4.x; c[2][1] += a4.z * b4.y; c[2][2] += a4.z * b4.z; c[2][3] += a4.z * b4.w;
            c[3][0] += a4.w * b4.x; c[3][1] += a4.w * b4.y; c[3][2] += a4.w * b4.z; c[3][3] += a4.w * b4.w;
        }
    }

    const int mrow = m0 + tm * 4;
    #pragma unroll
    for (int i = 0; i < 4; i++) {
        #pragma unroll
        for (int j = 0; j < 4; j++) {
            const int n = n0 + tn * 4 + j;
            if (n < N) {
                float v = c[i][j] + bias[n];
                if (RELU) v = fmaxf(v, 0.f);
                C[(size_t)(mrow + i) * N + n] = v;
            }
        }
    }
}

// ---------------------------------------------------------------------------
// fp32 GEMM (B not transposed): C[M,N] = A[M,K] @ B[K,N]. No bias.
// Used once: W_comb[6144,64] = w_ih[6144,2048] @ enc_w[2048,64].
// ---------------------------------------------------------------------------
__global__ __launch_bounds__(256) void sgemm_nn(
    const float* __restrict__ A, const float* __restrict__ B,
    float* __restrict__ C, int M, int N, int K)
{
    __shared__ float As[16][64];
    __shared__ float Bs[16][64];
    const int tid = threadIdx.x;
    const int tm = tid & 15;
    const int tn = tid >> 4;
    const int m0 = blockIdx.y * 64;
    const int n0 = blockIdx.x * 64;
    const int lm = tid >> 2;
    const int lk = (tid & 3) * 4;
    const int bk  = tid >> 4;
    const int bn4 = (tid & 15) * 4;

    float c[4][4] = {};

    for (int k0 = 0; k0 < K; k0 += 16) {
        float4 av = *(const float4*)(A + (size_t)(m0 + lm) * K + k0 + lk);
        float4 bv = *(const float4*)(B + (size_t)(k0 + bk) * N + n0 + bn4);
        __syncthreads();
        As[lk+0][lm] = av.x; As[lk+1][lm] = av.y; As[lk+2][lm] = av.z; As[lk+3][lm] = av.w;
        *(float4*)&Bs[bk][bn4] = bv;
        __syncthreads();
        #pragma unroll
        for (int kk = 0; kk < 16; kk++) {
            float4 a4 = *(const float4*)&As[kk][tm * 4];
            float4 b4 = *(const float4*)&Bs[kk][tn * 4];
            c[0][0] += a4.x * b4.x; c[0][1] += a4.x * b4.y; c[0][2] += a4.x * b4.z; c[0][3] += a4.x * b4.w;
            c[1][0] += a4.y * b4.x; c[1][1] += a4.y * b4.y; c[1][2] += a4.y * b4.z; c[1][3] += a4.y * b4.w;
            c[2][0] += a4.z * b4.x; c[2][1] += a4.z * b4.y; c[2][2] += a4.z * b4.z; c[2][3] += a4.z * b4.w;
            c[3][0] += a4.w * b4.x; c[3][1] += a4.w * b4.y; c[3][2] += a4.w * b4.z; c[3][3] += a4.w * b4.w;
        }
    }

    const int mrow = m0 + tm * 4;
    #pragma unroll
    for (int i = 0; i < 4; i++) {
        #pragma unroll
        for (int j = 0; j < 4; j++)
            C[(size_t)(mrow + i) * N + n0 + tn * 4 + j] = c[i][j];
    }
}

// ---------------------------------------------------------------------------
// b_comb[r] = dot(w_ih[r,:], enc_b) + b_ih[r].  One wave per row.
// ---------------------------------------------------------------------------
__global__ __launch_bounds__(256) void bcomb_kernel(
    const float* __restrict__ w_ih, const float* __restrict__ enc_b,
    const float* __restrict__ b_ih, float* __restrict__ b_comb)
{
    const int wv = threadIdx.x >> 6, lane = threadIdx.x & 63;
    const int r = blockIdx.x * 4 + wv;
    const float* row = w_ih + (size_t)r * HID;
    float acc = 0.f;
    for (int j = lane; j < HID; j += 64) acc += row[j] * enc_b[j];
    #pragma unroll
    for (int m = 32; m >= 1; m >>= 1) acc += __shfl_xor(acc, m, 64);
    if (lane == 0) b_comb[r] = acc + b_ih[r];
}

// ---------------------------------------------------------------------------
// Persistent GRU scan. 256 blocks x 1024 threads.
// R7 structure (proven 5.95 ms/dispatch): fused h+stamp 16B atoms, early
// spin, no end barrier, self-atom gating, fast gates, lgkm-only barriers.
// R9: XCD RELAY. Every atom was polled by 256 blocks (4MB of coherent IC
// reads per poll round, chip-wide) -> IC queueing inflates the discovery
// RTT ~3x. Per XCD: one elected leader block polls the global IC atoms
// (8 readers/atom instead of 256) and republishes each discovered atom
// (stamp copied verbatim -> same fused atomicity + monotonicity proof) to
// an XCD-local relay via sc0-only stores (shared per-XCD L2). Followers
// spin on the relay with sc0 loads: ~300cy L2 RTT, zero IC traffic.
// SAFETY VALVE: followers poll the global atom after 32 relay misses, so
// a wrong XCC_ID read or sc0 visibility surprise degrades to R7 perf
// instead of deadlocking.
// ---------------------------------------------------------------------------
__global__ __launch_bounds__(1024, 4) void gru_scan(
    const float* __restrict__ w_hh, const float* __restrict__ b_n,
    const float* __restrict__ ig,   // [steps,3,H] fp32 for this chunk
    float* __restrict__ hs,         // [steps,H] output states (chunk base)
    float4* __restrict__ atoms,     // 2 x 1024 global atoms, zeroed at launch
    float4* __restrict__ relay,     // 8 XCD x 2 x 1024 relay atoms, zeroed
    int* __restrict__ elect,        // per-chunk x 8 leader-election slots
    int base, int steps)
{
    __shared__ float h_lds[HID];
    __shared__ float pg[16][3];
    __shared__ float hg_lds[24];
    __shared__ int lead_s, xcd_s;
    const int tid  = threadIdx.x;
    const int lane = tid & 63;
    const int w    = tid >> 6;      // wave 0..15
    const int pr   = tid & 127;     // pair-local lane 0..127
    const int k    = tid >> 7;      // wave-pair 0..7
    const int b    = blockIdx.x;

    // ---- leader election per XCD (hwreg 20 = XCC_ID, user-readable) ----
    if (tid == 0) {
        int xcd;
        asm volatile("s_getreg_b32 %0, hwreg(20, 0, 32)" : "=s"(xcd));
        xcd &= 7;
        xcd_s  = xcd;
        lead_s = (atomicAdd(elect + (base / CHUNK) * 8 + xcd, 1) == 0) ? 1 : 0;
    }
    __syncthreads();
    const int  xcd    = xcd_s;
    const bool leader = (lead_s != 0);
    float4* rbase = relay + (size_t)xcd * 2048;

    // ---- 48 weights per thread (12 float4), coalesced ----
    // rows idx3 = 3k+j ; cols 4*pr + 512*m (m=0..3)
    float4 wreg[3][4];
    #pragma unroll
    for (int j = 0; j < 3; j++) {
        const int idx3 = 3 * k + j;
        const float* wp = w_hh +
            (size_t)((idx3 >> 3) * HID + b * 8 + (idx3 & 7)) * HID;
        #pragma unroll
        for (int m = 0; m < 4; m++)
            wreg[j][m] = *(const float4*)(wp + 4 * pr + 512 * m);
    }

    const int i = b * 8 + tid;                 // valid for tid<8
    const float bn = (tid < 8) ? b_n[i] : 0.f;

    for (int t = 0; t < steps; t++) {
        // ig loads for this step (tid<8, wave 0) - in flight during poll
        float ig0 = 0.f, ig1 = 0.f, ig2 = 0.f;
        if (tid < 8) {
            const float* p = ig + (size_t)t * H3 + i;
            ig0 = p[0]; ig1 = p[HID]; ig2 = p[2 * HID];
        }

        // ---- discovery: leader polls IC, republishes; follower polls L2 ----
        const float target = (float)(base + t);          // exact in fp32
        const float* ap = (const float*)(atoms + (t & 1) * 1024 + tid);
        float4* rp = rbase + (t & 1) * 1024 + tid;
        float4 f;
        if (leader) {
            f = cload_f4(ap);
            while (f.z < target) f = cload_f4(ap);
            cstore_f4_l(rp, f.x, f.y, f.z, 0.f);   // republish to XCD L2
        } else {
            int miss = 0;
            for (;;) {
                f = cload_f4_l((const float*)rp);
                if (f.z >= target) break;
                if (++miss >= 32) {                // valve: relay broken/slow
                    f = cload_f4(ap);
                    if (f.z >= target) break;
                    miss = 16;
                }
            }
        }
        *(float2*)&h_lds[2 * tid] = make_float2(f.x, f.y);
        BAR_LDS();

        // ---- dot: rows 3k..3k+2, cols 4*pr+512m, weights in registers ----
        float a0 = 0.f, a1 = 0.f, a2 = 0.f;
        #pragma unroll
        for (int m = 0; m < 4; m++) {
            float4 h4 = *(const float4*)&h_lds[4 * pr + 512 * m];
            a0 += wreg[0][m].x * h4.x + wreg[0][m].y * h4.y + wreg[0][m].z * h4.z + wreg[0][m].w * h4.w;
            a1 += wreg[1][m].x * h4.x + wreg[1][m].y * h4.y + wreg[1][m].z * h4.z + wreg[1][m].w * h4.w;
            a2 += wreg[2][m].x * h4.x + wreg[2][m].y * h4.y + wreg[2][m].z * h4.z + wreg[2][m].w * h4.w;
        }
        #pragma unroll
        for (int s = 32; s >= 1; s >>= 1) {
            a0 += __shfl_xor(a0, s, 64);
            a1 += __shfl_xor(a1, s, 64);
            a2 += __shfl_xor(a2, s, 64);
        }
        if (lane == 0) { pg[w][0] = a0; pg[w][1] = a1; pg[w][2] = a2; }
        BAR_LDS();

        // ---- combine + gates + publish (all in wave 0, lockstep) ----
        if (w == 0) {
            if (lane < 24) {
                const int kk = lane / 3, j = lane - 3 * kk;
                hg_lds[lane] = pg[2 * kk][j] + pg[2 * kk + 1][j];
            }
            asm volatile("s_waitcnt lgkmcnt(0)" ::: "memory");  // intra-wave LDS wr->rd
            float h_new = 0.f;
            if (lane < 8) {
                const float r = fsigmoid(ig0 + hg_lds[lane]);
                const float z = fsigmoid(ig1 + hg_lds[8 + lane]);
                const float n = ftanh_(ig2 + r * (hg_lds[16 + lane] + bn));
                const float hp = h_lds[i];
                h_new = n + z * (hp - n);
            }
            const float ha = __shfl(h_new, lane * 2, 64);
            const float hb = __shfl(h_new, lane * 2 + 1, 64);
            if (lane < 4) {
                cstore_f4(atoms + ((t + 1) & 1) * 1024 + b * 4 + lane,
                          ha, hb, (float)(base + t + 1), 0.f);
            }
            if (lane < 8)
                hs[(size_t)t * HID + i] = h_new;  // cached store, off critical path
        }
        // no end barrier: self-atom gating + top barrier provide ordering
    }
}

// ---------------------------------------------------------------------------
extern "C" void kernel_launch(void* const* d_in, const int* in_sizes, int n_in,
                              void* d_out, int out_size, void* d_ws, size_t ws_size,
                              hipStream_t stream) {
    const float* x     = (const float*)d_in[0];
    const float* enc_w = (const float*)d_in[1];
    const float* enc_b = (const float*)d_in[2];
    const float* w_ih  = (const float*)d_in[3];
    const float* w_hh  = (const float*)d_in[4];
    const float* b_ih  = (const float*)d_in[5];
    const float* b_n   = (const float*)d_in[6];
    const float* w0    = (const float*)d_in[7];
    const float* b0    = (const float*)d_in[8];
    const float* w1    = (const float*)d_in[9];
    const float* b1    = (const float*)d_in[10];
    const float* w2    = (const float*)d_in[11];
    const float* b2    = (const float*)d_in[12];
    float* out = (float*)d_out;

    // workspace (~136 MB): R1 64MB (ig chunk -> dec h1), R2 64MB (hs -> dec h2)
    float* R1    = (float*)d_ws;                          // 16,777,216 f
    float* R2    = R1 + (size_t)16777216;                 // 16,777,216 f
    float* wcomb = R2 + (size_t)16777216;                 // 393,216 f
    float* bcomb = wcomb + 393216;                        // 6,144 f
    float4* atoms = (float4*)(bcomb + 6144);              // 2*1024 float4 = 32KB
    // relay/elect live in R1's slack (ig uses 12.58M of 16.77M floats);
    // only needed during gru_scan, clobbered by the decoder afterwards.
    float4* relay = (float4*)(R1 + (size_t)13000000);     // 8*2*1024 f4 = 256KB
    int*    elect = (int*)(relay + 8 * 2048);             // 4 chunks * 8 ints

    (void)hipMemsetAsync(atoms, 0, 2 * 1024 * sizeof(float4), stream);
    (void)hipMemsetAsync(relay, 0, 8 * 2048 * sizeof(float4) + 32 * sizeof(int),
                         stream);

    // fold encoder into GRU input weights:
    //   W_comb = w_ih @ enc_w   [6144,64];  b_comb = w_ih @ enc_b + b_ih
    sgemm_nn<<<dim3(1, 96), 256, 0, stream>>>(w_ih, enc_w, wcomb, 6144, 64, 2048);
    bcomb_kernel<<<dim3(1536), 256, 0, stream>>>(w_ih, enc_b, b_ih, bcomb);

    // chunked: ig = x @ W_comb^T + b_comb (K=64), then sequential scan
    for (int c = 0; c < T_STEPS / CHUNK; c++) {
        sgemm_bias<0><<<dim3(H3 / 64, CHUNK / 64), 256, 0, stream>>>(
            x + (size_t)c * CHUNK * 64, wcomb, bcomb, R1, CHUNK, H3, 64);
        gru_scan<<<dim3(NBLK), dim3(1024), 0, stream>>>(
            w_hh, b_n, R1, R2 + (size_t)c * CHUNK * HID, atoms, relay, elect,
            c * CHUNK, CHUNK);
    }

    // decoder MLP (aliased: R2=hs -> R1=h1 -> R2=h2 -> out)
    sgemm_bias<1><<<dim3(HID / 64, T_STEPS / 64), 256, 0, stream>>>(
        R2, w0, b0, R1, T_STEPS, HID, HID);
    sgemm_bias<1><<<dim3(HID / 64, T_STEPS / 64), 256, 0, stream>>>(
        R1, w1, b1, R2, T_STEPS, HID, HID);
    sgemm_bias<0><<<dim3(1, T_STEPS / 64), 256, 0, stream>>>(
        R2, w2, b2, out, T_STEPS, 49, 2048);
}

// Round 7
// 54690.839 us; speedup vs baseline: 1.3181x; 1.3181x over previous
//
#include <hip/hip_runtime.h>
#include <math.h>

#define T_STEPS 8192
#define HID 2048
#define H3 6144
#define NBLK 256
#define CHUNK 2048

typedef float f32x4 __attribute__((ext_vector_type(4)));
typedef float f32x2 __attribute__((ext_vector_type(2)));

// ---------------------------------------------------------------------------
// Coherent (cross-XCD) access: sc0 sc1 = Infinity-Cache coherence point.
// PROTOCOL IS SETTLED (R4..R9): distributed fused data+stamp atoms, early
// spin, no end barrier. Falsified alternatives: end-barrier (+60%, R5),
// centralized flags (+580%, R6), split-issue pipelined poll (corrupt, R8),
// XCD leader relay (+800%, R9). Load+waitcnt MUST stay fused in one asm
// statement (R8 lesson).
// R10 lesson: distributed gates REQUIRE the (g*HID + b*8 + k) weight
// mapping — pair k owns all three gates of row k. Keeping R4's idx3=3k+j
// flattened mapping silently computes wrong-row partials (absmax 2.6e-2).
// ---------------------------------------------------------------------------
__device__ __forceinline__ float4 cload_f4(const float* p) {
    float4 r;
    asm volatile("global_load_dwordx4 %0, %1, off sc0 sc1\n\t"
                 "s_waitcnt vmcnt(0)"
                 : "=&v"(r) : "v"(p) : "memory");
    return r;
}
__device__ __forceinline__ void cstore_f2(float2* p, float x, float y) {
    f32x2 v; v[0] = x; v[1] = y;
    asm volatile("global_store_dwordx2 %0, %1, off sc0 sc1"
                 :: "v"(p), "v"(v) : "memory");
}

// LDS-only barrier: __syncthreads() drains vmcnt too; these barriers only
// order LDS traffic -> drain lgkmcnt only, leave vmem acks in flight (R7).
#define BAR_LDS() asm volatile("s_waitcnt lgkmcnt(0)\n\ts_barrier" ::: "memory")

// ---------------------------------------------------------------------------
// Fast gates: v_exp_f32 (2^x) based sigmoid/tanh (R7, validated: -6%).
// ---------------------------------------------------------------------------
__device__ __forceinline__ float fexp2(float x) {
    return __builtin_amdgcn_exp2f(x);
}
__device__ __forceinline__ float frcp(float x) { return __builtin_amdgcn_rcpf(x); }
__device__ __forceinline__ float fsigmoid(float x) {
    return frcp(1.f + fexp2(-1.44269504089f * x));
}
__device__ __forceinline__ float ftanh_(float x) {
    return 2.f * frcp(1.f + fexp2(-2.88539008178f * x)) - 1.f;
}

// ---------------------------------------------------------------------------
// fp32 GEMM: C[M,N] = A[M,K] @ B[N,K]^T + bias, optional ReLU.
// ---------------------------------------------------------------------------
template<int RELU>
__global__ __launch_bounds__(256) void sgemm_bias(
    const float* __restrict__ A, const float* __restrict__ B,
    const float* __restrict__ bias, float* __restrict__ C,
    int M, int N, int K)
{
    __shared__ float As[16][64];
    __shared__ float Bs[16][64];
    const int tid = threadIdx.x;
    const int tm = tid & 15;
    const int tn = tid >> 4;
    const int m0 = blockIdx.y * 64;
    const int n0 = blockIdx.x * 64;
    const int lm = tid >> 2;
    const int lk = (tid & 3) * 4;

    float c[4][4] = {};

    for (int k0 = 0; k0 < K; k0 += 16) {
        float4 av = *(const float4*)(A + (size_t)(m0 + lm) * K + k0 + lk);
        float4 bv = make_float4(0.f, 0.f, 0.f, 0.f);
        const int bn = n0 + lm;
        if (bn < N) bv = *(const float4*)(B + (size_t)bn * K + k0 + lk);
        __syncthreads();
        As[lk+0][lm] = av.x; As[lk+1][lm] = av.y; As[lk+2][lm] = av.z; As[lk+3][lm] = av.w;
        Bs[lk+0][lm] = bv.x; Bs[lk+1][lm] = bv.y; Bs[lk+2][lm] = bv.z; Bs[lk+3][lm] = bv.w;
        __syncthreads();
        #pragma unroll
        for (int kk = 0; kk < 16; kk++) {
            float4 a4 = *(const float4*)&As[kk][tm * 4];
            float4 b4 = *(const float4*)&Bs[kk][tn * 4];
            c[0][0] += a4.x * b4.x; c[0][1] += a4.x * b4.y; c[0][2] += a4.x * b4.z; c[0][3] += a4.x * b4.w;
            c[1][0] += a4.y * b4.x; c[1][1] += a4.y * b4.y; c[1][2] += a4.y * b4.z; c[1][3] += a4.y * b4.w;
            c[2][0] += a4.z * b4.x; c[2][1] += a4.z * b4.y; c[2][2] += a4.z * b4.z; c[2][3] += a4.z * b4.w;
            c[3][0] += a4.w * b4.x; c[3][1] += a4.w * b4.y; c[3][2] += a4.w * b4.z; c[3][3] += a4.w * b4.w;
        }
    }

    const int mrow = m0 + tm * 4;
    #pragma unroll
    for (int i = 0; i < 4; i++) {
        #pragma unroll
        for (int j = 0; j < 4; j++) {
            const int n = n0 + tn * 4 + j;
            if (n < N) {
                float v = c[i][j] + bias[n];
                if (RELU) v = fmaxf(v, 0.f);
                C[(size_t)(mrow + i) * N + n] = v;
            }
        }
    }
}

// ---------------------------------------------------------------------------
// fp32 GEMM (B not transposed): C[M,N] = A[M,K] @ B[K,N]. No bias.
// Used once: W_comb[6144,64] = w_ih[6144,2048] @ enc_w[2048,64].
// ---------------------------------------------------------------------------
__global__ __launch_bounds__(256) void sgemm_nn(
    const float* __restrict__ A, const float* __restrict__ B,
    float* __restrict__ C, int M, int N, int K)
{
    __shared__ float As[16][64];
    __shared__ float Bs[16][64];
    const int tid = threadIdx.x;
    const int tm = tid & 15;
    const int tn = tid >> 4;
    const int m0 = blockIdx.y * 64;
    const int n0 = blockIdx.x * 64;
    const int lm = tid >> 2;
    const int lk = (tid & 3) * 4;
    const int bk  = tid >> 4;
    const int bn4 = (tid & 15) * 4;

    float c[4][4] = {};

    for (int k0 = 0; k0 < K; k0 += 16) {
        float4 av = *(const float4*)(A + (size_t)(m0 + lm) * K + k0 + lk);
        float4 bv = *(const float4*)(B + (size_t)(k0 + bk) * N + n0 + bn4);
        __syncthreads();
        As[lk+0][lm] = av.x; As[lk+1][lm] = av.y; As[lk+2][lm] = av.z; As[lk+3][lm] = av.w;
        *(float4*)&Bs[bk][bn4] = bv;
        __syncthreads();
        #pragma unroll
        for (int kk = 0; kk < 16; kk++) {
            float4 a4 = *(const float4*)&As[kk][tm * 4];
            float4 b4 = *(const float4*)&Bs[kk][tn * 4];
            c[0][0] += a4.x * b4.x; c[0][1] += a4.x * b4.y; c[0][2] += a4.x * b4.z; c[0][3] += a4.x * b4.w;
            c[1][0] += a4.y * b4.x; c[1][1] += a4.y * b4.y; c[1][2] += a4.y * b4.z; c[1][3] += a4.y * b4.w;
            c[2][0] += a4.z * b4.x; c[2][1] += a4.z * b4.y; c[2][2] += a4.z * b4.z; c[2][3] += a4.z * b4.w;
            c[3][0] += a4.w * b4.x; c[3][1] += a4.w * b4.y; c[3][2] += a4.w * b4.z; c[3][3] += a4.w * b4.w;
        }
    }

    const int mrow = m0 + tm * 4;
    #pragma unroll
    for (int i = 0; i < 4; i++) {
        #pragma unroll
        for (int j = 0; j < 4; j++)
            C[(size_t)(mrow + i) * N + n0 + tn * 4 + j] = c[i][j];
    }
}

// ---------------------------------------------------------------------------
// b_comb[r] = dot(w_ih[r,:], enc_b) + b_ih[r].  One wave per row.
// ---------------------------------------------------------------------------
__global__ __launch_bounds__(256) void bcomb_kernel(
    const float* __restrict__ w_ih, const float* __restrict__ enc_b,
    const float* __restrict__ b_ih, float* __restrict__ b_comb)
{
    const int wv = threadIdx.x >> 6, lane = threadIdx.x & 63;
    const int r = blockIdx.x * 4 + wv;
    const float* row = w_ih + (size_t)r * HID;
    float acc = 0.f;
    for (int j = lane; j < HID; j += 64) acc += row[j] * enc_b[j];
    #pragma unroll
    for (int m = 32; m >= 1; m >>= 1) acc += __shfl_xor(acc, m, 64);
    if (lane == 0) b_comb[r] = acc + b_ih[r];
}

// ---------------------------------------------------------------------------
// Persistent GRU scan. 256 blocks x 1024 threads, 1 block/CU.
// R7 exchange EXACTLY (fused data+stamp atoms, early spin, no end barrier,
// lgkm-only barriers, fast gates).
// R11 = R10 distributed gates with the CORRECT weight mapping (R5's):
// pair k (waves 2k,2k+1) owns h-row irow=b*8+k and all THREE gate rows
// (g*HID + irow for g=0,1,2). After the butterfly, lane 0 of the EVEN wave
// adds its partner's partials from pg (ordered by 2nd BAR_LDS), computes
// gates for row irow, publishes an 8B {h_new, stamp} atom directly.
// Deletes the centralized wave-0 stage (hg_lds round trip + 2 shfl
// broadcasts, ~300-500cy serial tail); 8 gate computations run in 8 waves
// in parallel. Consumer polls ONE 16B load covering atoms 2tid,2tid+1 and
// checks BOTH stamps (R5-proven consumer).
// Ordering proofs unchanged: pg reads@t precede pg writes@t+1 via the top
// barrier (gate_th must arrive); h_lds[irow] reads precede overwrites via
// self-atom gating (the t+1 overwriter polls atoms published by this pair
// only after the hp read).
// ---------------------------------------------------------------------------
__global__ __launch_bounds__(1024, 4) void gru_scan(
    const float* __restrict__ w_hh, const float* __restrict__ b_n,
    const float* __restrict__ ig,   // [steps,3,H] fp32 for this chunk
    float* __restrict__ hs,         // [steps,H] output states (chunk base)
    float2* __restrict__ atoms,     // 2 x 2048 {h,stamp} atoms, zeroed
    int base, int steps)
{
    __shared__ float h_lds[HID];
    __shared__ float pg[16][3];
    const int tid  = threadIdx.x;
    const int lane = tid & 63;
    const int w    = tid >> 6;      // wave 0..15
    const int pr   = tid & 127;     // pair-local lane 0..127
    const int k    = tid >> 7;      // wave-pair 0..7 -> owns h-row b*8+k
    const int b    = blockIdx.x;

    // ---- 48 weights per thread (12 float4) ----
    // gate g row of h-row k:  w_hh[(g*HID + b*8 + k), :]   cols 4*pr + 512*m
    float4 wreg[3][4];
    #pragma unroll
    for (int g = 0; g < 3; g++) {
        const float* wp = w_hh + (size_t)(g * HID + b * 8 + k) * HID;
        #pragma unroll
        for (int m = 0; m < 4; m++)
            wreg[g][m] = *(const float4*)(wp + 4 * pr + 512 * m);
    }

    const int  irow    = b * 8 + k;          // this pair's h row
    const bool gate_th = ((tid & 127) == 0); // lane 0 of even wave
    const float bn = b_n[irow];

    for (int t = 0; t < steps; t++) {
        // ig loads for this step (8 gate threads) - in flight during poll
        float ig0 = 0.f, ig1 = 0.f, ig2 = 0.f;
        if (gate_th) {
            const float* p = ig + (size_t)t * H3 + irow;
            ig0 = p[0]; ig1 = p[HID]; ig2 = p[2 * HID];
        }

        // ---- poll own atoms: one 16B IC round trip, two fused stamps ----
        const float target = (float)(base + t);          // exact in fp32
        const float* ap = (const float*)(atoms + (size_t)(t & 1) * 2048 + 2 * tid);
        float4 f;  // {h[2tid], stamp, h[2tid+1], stamp}
        do { f = cload_f4(ap); } while (f.y < target || f.w < target);
        *(float2*)&h_lds[2 * tid] = make_float2(f.x, f.z);
        BAR_LDS();

        // ---- dot: 3 gate rows of h-row irow, cols 4*pr+512m ----
        float a0 = 0.f, a1 = 0.f, a2 = 0.f;
        #pragma unroll
        for (int m = 0; m < 4; m++) {
            float4 h4 = *(const float4*)&h_lds[4 * pr + 512 * m];
            a0 += wreg[0][m].x * h4.x + wreg[0][m].y * h4.y + wreg[0][m].z * h4.z + wreg[0][m].w * h4.w;
            a1 += wreg[1][m].x * h4.x + wreg[1][m].y * h4.y + wreg[1][m].z * h4.z + wreg[1][m].w * h4.w;
            a2 += wreg[2][m].x * h4.x + wreg[2][m].y * h4.y + wreg[2][m].z * h4.z + wreg[2][m].w * h4.w;
        }
        #pragma unroll
        for (int s = 32; s >= 1; s >>= 1) {
            a0 += __shfl_xor(a0, s, 64);
            a1 += __shfl_xor(a1, s, 64);
            a2 += __shfl_xor(a2, s, 64);
        }
        // odd wave of each pair deposits its wave-sum for the even wave
        if ((w & 1) && lane == 0) { pg[w][0] = a0; pg[w][1] = a1; pg[w][2] = a2; }
        BAR_LDS();

        // ---- gates + publish: 8 parallel gate threads, no central stage ----
        if (gate_th) {
            const float hg0 = a0 + pg[w + 1][0];
            const float hg1 = a1 + pg[w + 1][1];
            const float hg2 = a2 + pg[w + 1][2];
            const float r = fsigmoid(ig0 + hg0);
            const float z = fsigmoid(ig1 + hg1);
            const float n = ftanh_(ig2 + r * (hg2 + bn));
            const float hp = h_lds[irow];
            const float h_new = n + z * (hp - n);
            cstore_f2(atoms + (size_t)((t + 1) & 1) * 2048 + irow,
                      h_new, target + 1.f);
            hs[(size_t)t * HID + irow] = h_new;  // cached store, after publish
        }
        // no end barrier: self-atom gating + top barrier provide ordering
    }
}

// ---------------------------------------------------------------------------
extern "C" void kernel_launch(void* const* d_in, const int* in_sizes, int n_in,
                              void* d_out, int out_size, void* d_ws, size_t ws_size,
                              hipStream_t stream) {
    const float* x     = (const float*)d_in[0];
    const float* enc_w = (const float*)d_in[1];
    const float* enc_b = (const float*)d_in[2];
    const float* w_ih  = (const float*)d_in[3];
    const float* w_hh  = (const float*)d_in[4];
    const float* b_ih  = (const float*)d_in[5];
    const float* b_n   = (const float*)d_in[6];
    const float* w0    = (const float*)d_in[7];
    const float* b0    = (const float*)d_in[8];
    const float* w1    = (const float*)d_in[9];
    const float* b1    = (const float*)d_in[10];
    const float* w2    = (const float*)d_in[11];
    const float* b2    = (const float*)d_in[12];
    float* out = (float*)d_out;

    // workspace (~136 MB): R1 64MB (ig chunk -> dec h1), R2 64MB (hs -> dec h2)
    float* R1    = (float*)d_ws;                          // 16,777,216 f
    float* R2    = R1 + (size_t)16777216;                 // 16,777,216 f
    float* wcomb = R2 + (size_t)16777216;                 // 393,216 f
    float* bcomb = wcomb + 393216;                        // 6,144 f
    float2* atoms = (float2*)(bcomb + 6144);              // 2*2048 float2 = 32KB

    (void)hipMemsetAsync(atoms, 0, 2 * 2048 * sizeof(float2), stream);

    // fold encoder into GRU input weights:
    //   W_comb = w_ih @ enc_w   [6144,64];  b_comb = w_ih @ enc_b + b_ih
    sgemm_nn<<<dim3(1, 96), 256, 0, stream>>>(w_ih, enc_w, wcomb, 6144, 64, 2048);
    bcomb_kernel<<<dim3(1536), 256, 0, stream>>>(w_ih, enc_b, b_ih, bcomb);

    // chunked: ig = x @ W_comb^T + b_comb (K=64), then sequential scan
    for (int c = 0; c < T_STEPS / CHUNK; c++) {
        sgemm_bias<0><<<dim3(H3 / 64, CHUNK / 64), 256, 0, stream>>>(
            x + (size_t)c * CHUNK * 64, wcomb, bcomb, R1, CHUNK, H3, 64);
        gru_scan<<<dim3(NBLK), dim3(1024), 0, stream>>>(
            w_hh, b_n, R1, R2 + (size_t)c * CHUNK * HID, atoms, c * CHUNK, CHUNK);
    }

    // decoder MLP (aliased: R2=hs -> R1=h1 -> R2=h2 -> out)
    sgemm_bias<1><<<dim3(HID / 64, T_STEPS / 64), 256, 0, stream>>>(
        R2, w0, b0, R1, T_STEPS, HID, HID);
    sgemm_bias<1><<<dim3(HID / 64, T_STEPS / 64), 256, 0, stream>>>(
        R1, w1, b1, R2, T_STEPS, HID, HID);
    sgemm_bias<0><<<dim3(1, T_STEPS / 64), 256, 0, stream>>>(
        R2, w2, b2, out, T_STEPS, 49, 2048);
}

// Round 8
// 25781.131 us; speedup vs baseline: 2.7962x; 2.1214x over previous
//
#include <hip/hip_runtime.h>
#include <math.h>

#define T_STEPS 8192
#define HID 2048
#define H3 6144
#define NBLK 256
#define CHUNK 2048

typedef float f32x4 __attribute__((ext_vector_type(4)));

// ---------------------------------------------------------------------------
// Coherent (cross-XCD) access: sc0 sc1 bypasses L1/L2 to the Infinity-Cache
// coherence point. PROTOCOL SETTLED (R4..R11): distributed fused data+stamp
// 16B atoms, per-thread poll addresses, early spin, no end barrier,
// CENTRALIZED lockstep wave-0 publish. Falsified alternatives:
//   R5  end-of-step barrier               +60%  (early spin is prefetch)
//   R6  centralized 4B flag lines        +580%  (IC hot-line serialization)
//   R8  split-issue pipelined poll     corrupt  (reg-lifetime; fused
//                                               load+waitcnt is mandatory)
//   R9  XCD leader relay                 +800%  (serial hop, leader-paced)
//   R11 distributed gates / 8B atoms     +107%  (publish-time variance:
//       release = max over stamps; lockstep publish minimizes the max)
// ---------------------------------------------------------------------------
__device__ __forceinline__ float4 cload_f4(const float* p) {
    float4 r;
    asm volatile("global_load_dwordx4 %0, %1, off sc0 sc1\n\t"
                 "s_waitcnt vmcnt(0)"
                 : "=&v"(r) : "v"(p) : "memory");
    return r;
}
__device__ __forceinline__ void cstore_f4(float4* p, float x, float y,
                                          float z, float w) {
    f32x4 v; v[0] = x; v[1] = y; v[2] = z; v[3] = w;
    asm volatile("global_store_dwordx4 %0, %1, off sc0 sc1"
                 :: "v"(p), "v"(v) : "memory");
}

// LDS-only barrier: __syncthreads() drains vmcnt too, which serializes
// outstanding ig-load / hs-store acks into the barrier. These barriers only
// order LDS traffic -> drain lgkmcnt only, leave vmem in flight. (R7, -6%)
#define BAR_LDS() asm volatile("s_waitcnt lgkmcnt(0)\n\ts_barrier" ::: "memory")

// ---------------------------------------------------------------------------
// Fast gates: v_exp_f32 (2^x) based sigmoid/tanh (R7, validated).
// Saturation: exp2(-inf)->0 (sig->1), exp2(+inf)->inf->rcp->0 (sig->0).
// ---------------------------------------------------------------------------
__device__ __forceinline__ float fexp2(float x) {
    return __builtin_amdgcn_exp2f(x);
}
__device__ __forceinline__ float frcp(float x) { return __builtin_amdgcn_rcpf(x); }
__device__ __forceinline__ float fsigmoid(float x) {
    return frcp(1.f + fexp2(-1.44269504089f * x));
}
__device__ __forceinline__ float ftanh_(float x) {
    return 2.f * frcp(1.f + fexp2(-2.88539008178f * x)) - 1.f;
}

// ---------------------------------------------------------------------------
// fp32 GEMM: C[M,N] = A[M,K] @ B[N,K]^T + bias, optional ReLU.
// ---------------------------------------------------------------------------
template<int RELU>
__global__ __launch_bounds__(256) void sgemm_bias(
    const float* __restrict__ A, const float* __restrict__ B,
    const float* __restrict__ bias, float* __restrict__ C,
    int M, int N, int K)
{
    __shared__ float As[16][64];
    __shared__ float Bs[16][64];
    const int tid = threadIdx.x;
    const int tm = tid & 15;
    const int tn = tid >> 4;
    const int m0 = blockIdx.y * 64;
    const int n0 = blockIdx.x * 64;
    const int lm = tid >> 2;
    const int lk = (tid & 3) * 4;

    float c[4][4] = {};

    for (int k0 = 0; k0 < K; k0 += 16) {
        float4 av = *(const float4*)(A + (size_t)(m0 + lm) * K + k0 + lk);
        float4 bv = make_float4(0.f, 0.f, 0.f, 0.f);
        const int bn = n0 + lm;
        if (bn < N) bv = *(const float4*)(B + (size_t)bn * K + k0 + lk);
        __syncthreads();
        As[lk+0][lm] = av.x; As[lk+1][lm] = av.y; As[lk+2][lm] = av.z; As[lk+3][lm] = av.w;
        Bs[lk+0][lm] = bv.x; Bs[lk+1][lm] = bv.y; Bs[lk+2][lm] = bv.z; Bs[lk+3][lm] = bv.w;
        __syncthreads();
        #pragma unroll
        for (int kk = 0; kk < 16; kk++) {
            float4 a4 = *(const float4*)&As[kk][tm * 4];
            float4 b4 = *(const float4*)&Bs[kk][tn * 4];
            c[0][0] += a4.x * b4.x; c[0][1] += a4.x * b4.y; c[0][2] += a4.x * b4.z; c[0][3] += a4.x * b4.w;
            c[1][0] += a4.y * b4.x; c[1][1] += a4.y * b4.y; c[1][2] += a4.y * b4.z; c[1][3] += a4.y * b4.w;
            c[2][0] += a4.z * b4.x; c[2][1] += a4.z * b4.y; c[2][2] += a4.z * b4.z; c[2][3] += a4.z * b4.w;
            c[3][0] += a4.w * b4.x; c[3][1] += a4.w * b4.y; c[3][2] += a4.w * b4.z; c[3][3] += a4.w * b4.w;
        }
    }

    const int mrow = m0 + tm * 4;
    #pragma unroll
    for (int i = 0; i < 4; i++) {
        #pragma unroll
        for (int j = 0; j < 4; j++) {
            const int n = n0 + tn * 4 + j;
            if (n < N) {
                float v = c[i][j] + bias[n];
                if (RELU) v = fmaxf(v, 0.f);
                C[(size_t)(mrow + i) * N + n] = v;
            }
        }
    }
}

// ---------------------------------------------------------------------------
// fp32 GEMM (B not transposed): C[M,N] = A[M,K] @ B[K,N]. No bias.
// Used once: W_comb[6144,64] = w_ih[6144,2048] @ enc_w[2048,64].
// ---------------------------------------------------------------------------
__global__ __launch_bounds__(256) void sgemm_nn(
    const float* __restrict__ A, const float* __restrict__ B,
    float* __restrict__ C, int M, int N, int K)
{
    __shared__ float As[16][64];
    __shared__ float Bs[16][64];
    const int tid = threadIdx.x;
    const int tm = tid & 15;
    const int tn = tid >> 4;
    const int m0 = blockIdx.y * 64;
    const int n0 = blockIdx.x * 64;
    const int lm = tid >> 2;
    const int lk = (tid & 3) * 4;
    const int bk  = tid >> 4;
    const int bn4 = (tid & 15) * 4;

    float c[4][4] = {};

    for (int k0 = 0; k0 < K; k0 += 16) {
        float4 av = *(const float4*)(A + (size_t)(m0 + lm) * K + k0 + lk);
        float4 bv = *(const float4*)(B + (size_t)(k0 + bk) * N + n0 + bn4);
        __syncthreads();
        As[lk+0][lm] = av.x; As[lk+1][lm] = av.y; As[lk+2][lm] = av.z; As[lk+3][lm] = av.w;
        *(float4*)&Bs[bk][bn4] = bv;
        __syncthreads();
        #pragma unroll
        for (int kk = 0; kk < 16; kk++) {
            float4 a4 = *(const float4*)&As[kk][tm * 4];
            float4 b4 = *(const float4*)&Bs[kk][tn * 4];
            c[0][0] += a4.x * b4.x; c[0][1] += a4.x * b4.y; c[0][2] += a4.x * b4.z; c[0][3] += a4.x * b4.w;
            c[1][0] += a4.y * b4.x; c[1][1] += a4.y * b4.y; c[1][2] += a4.y * b4.z; c[1][3] += a4.y * b4.w;
            c[2][0] += a4.z * b4.x; c[2][1] += a4.z * b4.y; c[2][2] += a4.z * b4.z; c[2][3] += a4.z * b4.w;
            c[3][0] += a4.w * b4.x; c[3][1] += a4.w * b4.y; c[3][2] += a4.w * b4.z; c[3][3] += a4.w * b4.w;
        }
    }

    const int mrow = m0 + tm * 4;
    #pragma unroll
    for (int i = 0; i < 4; i++) {
        #pragma unroll
        for (int j = 0; j < 4; j++)
            C[(size_t)(mrow + i) * N + n0 + tn * 4 + j] = c[i][j];
    }
}

// ---------------------------------------------------------------------------
// b_comb[r] = dot(w_ih[r,:], enc_b) + b_ih[r].  One wave per row.
// ---------------------------------------------------------------------------
__global__ __launch_bounds__(256) void bcomb_kernel(
    const float* __restrict__ w_ih, const float* __restrict__ enc_b,
    const float* __restrict__ b_ih, float* __restrict__ b_comb)
{
    const int wv = threadIdx.x >> 6, lane = threadIdx.x & 63;
    const int r = blockIdx.x * 4 + wv;
    const float* row = w_ih + (size_t)r * HID;
    float acc = 0.f;
    for (int j = lane; j < HID; j += 64) acc += row[j] * enc_b[j];
    #pragma unroll
    for (int m = 32; m >= 1; m >>= 1) acc += __shfl_xor(acc, m, 64);
    if (lane == 0) b_comb[r] = acc + b_ih[r];
}

// ---------------------------------------------------------------------------
// Persistent GRU scan. 256 blocks x 1024 threads, 1 block/CU.
// BEST VERIFIED STRUCTURE (R7, 5.95 ms/dispatch, 25.83 ms total):
//  * fused h+stamp 16B atoms, per-thread distributed poll addresses
//  * early spin (poll starts before publish - load-bearing prefetch, R5)
//  * no end barrier; self-atom gating orders intra-block LDS reuse
//  * CENTRALIZED lockstep wave-0 publish (minimizes stamp-time variance;
//    the block release is a max over 1024 discoveries - R11)
//  * fast v_exp gates + lgkm-only barriers + post-publish hs store (R7)
// Structural floor: per step = one cross-XCD coherent publish->discover
// round trip + dot/reduce/tail; five independent structural probes
// (R5,R6,R8,R9,R11) all regressed. Do not touch the protocol.
// ---------------------------------------------------------------------------
__global__ __launch_bounds__(1024, 4) void gru_scan(
    const float* __restrict__ w_hh, const float* __restrict__ b_n,
    const float* __restrict__ ig,   // [steps,3,H] fp32 for this chunk
    float* __restrict__ hs,         // [steps,H] output states (chunk base)
    float4* __restrict__ atoms,     // 2 x 1024 atoms, zeroed at launch
    int base, int steps)
{
    __shared__ float h_lds[HID];
    __shared__ float pg[16][3];
    __shared__ float hg_lds[24];
    const int tid  = threadIdx.x;
    const int lane = tid & 63;
    const int w    = tid >> 6;      // wave 0..15
    const int pr   = tid & 127;     // pair-local lane 0..127
    const int k    = tid >> 7;      // wave-pair 0..7
    const int b    = blockIdx.x;

    // ---- 48 weights per thread (12 float4), coalesced ----
    // rows idx3 = 3k+j ; cols 4*pr + 512*m (m=0..3)
    float4 wreg[3][4];
    #pragma unroll
    for (int j = 0; j < 3; j++) {
        const int idx3 = 3 * k + j;
        const float* wp = w_hh +
            (size_t)((idx3 >> 3) * HID + b * 8 + (idx3 & 7)) * HID;
        #pragma unroll
        for (int m = 0; m < 4; m++)
            wreg[j][m] = *(const float4*)(wp + 4 * pr + 512 * m);
    }

    const int i = b * 8 + tid;                 // valid for tid<8
    const float bn = (tid < 8) ? b_n[i] : 0.f;

    for (int t = 0; t < steps; t++) {
        // ig loads for this step (tid<8, wave 0) - in flight during poll
        float ig0 = 0.f, ig1 = 0.f, ig2 = 0.f;
        if (tid < 8) {
            const float* p = ig + (size_t)t * H3 + i;
            ig0 = p[0]; ig1 = p[HID]; ig2 = p[2 * HID];
        }

        // ---- poll own atom: one IC round trip returns stamp AND data ----
        const float target = (float)(base + t);          // exact in fp32
        const float* ap = (const float*)(atoms + (t & 1) * 1024 + tid);
        float4 f;
        do { f = cload_f4(ap); } while (f.z < target);
        *(float2*)&h_lds[2 * tid] = make_float2(f.x, f.y);
        BAR_LDS();

        // ---- dot: rows 3k..3k+2, cols 4*pr+512m, weights in registers ----
        float a0 = 0.f, a1 = 0.f, a2 = 0.f;
        #pragma unroll
        for (int m = 0; m < 4; m++) {
            float4 h4 = *(const float4*)&h_lds[4 * pr + 512 * m];
            a0 += wreg[0][m].x * h4.x + wreg[0][m].y * h4.y + wreg[0][m].z * h4.z + wreg[0][m].w * h4.w;
            a1 += wreg[1][m].x * h4.x + wreg[1][m].y * h4.y + wreg[1][m].z * h4.z + wreg[1][m].w * h4.w;
            a2 += wreg[2][m].x * h4.x + wreg[2][m].y * h4.y + wreg[2][m].z * h4.z + wreg[2][m].w * h4.w;
        }
        #pragma unroll
        for (int s = 32; s >= 1; s >>= 1) {
            a0 += __shfl_xor(a0, s, 64);
            a1 += __shfl_xor(a1, s, 64);
            a2 += __shfl_xor(a2, s, 64);
        }
        if (lane == 0) { pg[w][0] = a0; pg[w][1] = a1; pg[w][2] = a2; }
        BAR_LDS();

        // ---- combine + gates + publish (all in wave 0, lockstep) ----
        if (w == 0) {
            if (lane < 24) {
                const int kk = lane / 3, j = lane - 3 * kk;
                hg_lds[lane] = pg[2 * kk][j] + pg[2 * kk + 1][j];
            }
            asm volatile("s_waitcnt lgkmcnt(0)" ::: "memory");  // intra-wave LDS wr->rd
            float h_new = 0.f;
            if (lane < 8) {
                const float r = fsigmoid(ig0 + hg_lds[lane]);
                const float z = fsigmoid(ig1 + hg_lds[8 + lane]);
                const float n = ftanh_(ig2 + r * (hg_lds[16 + lane] + bn));
                const float hp = h_lds[i];
                h_new = n + z * (hp - n);
            }
            const float ha = __shfl(h_new, lane * 2, 64);
            const float hb = __shfl(h_new, lane * 2 + 1, 64);
            if (lane < 4) {
                cstore_f4(atoms + ((t + 1) & 1) * 1024 + b * 4 + lane,
                          ha, hb, (float)(base + t + 1), 0.f);
            }
            if (lane < 8)
                hs[(size_t)t * HID + i] = h_new;  // cached store, off critical path
        }
        // no end barrier: self-atom gating + top barrier provide ordering
    }
}

// ---------------------------------------------------------------------------
extern "C" void kernel_launch(void* const* d_in, const int* in_sizes, int n_in,
                              void* d_out, int out_size, void* d_ws, size_t ws_size,
                              hipStream_t stream) {
    const float* x     = (const float*)d_in[0];
    const float* enc_w = (const float*)d_in[1];
    const float* enc_b = (const float*)d_in[2];
    const float* w_ih  = (const float*)d_in[3];
    const float* w_hh  = (const float*)d_in[4];
    const float* b_ih  = (const float*)d_in[5];
    const float* b_n   = (const float*)d_in[6];
    const float* w0    = (const float*)d_in[7];
    const float* b0    = (const float*)d_in[8];
    const float* w1    = (const float*)d_in[9];
    const float* b1    = (const float*)d_in[10];
    const float* w2    = (const float*)d_in[11];
    const float* b2    = (const float*)d_in[12];
    float* out = (float*)d_out;

    // workspace (~136 MB): R1 64MB (ig chunk -> dec h1), R2 64MB (hs -> dec h2)
    float* R1    = (float*)d_ws;                          // 16,777,216 f
    float* R2    = R1 + (size_t)16777216;                 // 16,777,216 f
    float* wcomb = R2 + (size_t)16777216;                 // 393,216 f
    float* bcomb = wcomb + 393216;                        // 6,144 f
    float4* atoms = (float4*)(bcomb + 6144);              // 2*1024 float4 = 32KB

    (void)hipMemsetAsync(atoms, 0, 2 * 1024 * sizeof(float4), stream);

    // fold encoder into GRU input weights:
    //   W_comb = w_ih @ enc_w   [6144,64];  b_comb = w_ih @ enc_b + b_ih
    sgemm_nn<<<dim3(1, 96), 256, 0, stream>>>(w_ih, enc_w, wcomb, 6144, 64, 2048);
    bcomb_kernel<<<dim3(1536), 256, 0, stream>>>(w_ih, enc_b, b_ih, bcomb);

    // chunked: ig = x @ W_comb^T + b_comb (K=64), then sequential scan
    for (int c = 0; c < T_STEPS / CHUNK; c++) {
        sgemm_bias<0><<<dim3(H3 / 64, CHUNK / 64), 256, 0, stream>>>(
            x + (size_t)c * CHUNK * 64, wcomb, bcomb, R1, CHUNK, H3, 64);
        gru_scan<<<dim3(NBLK), dim3(1024), 0, stream>>>(
            w_hh, b_n, R1, R2 + (size_t)c * CHUNK * HID, atoms, c * CHUNK, CHUNK);
    }

    // decoder MLP (aliased: R2=hs -> R1=h1 -> R2=h2 -> out)
    sgemm_bias<1><<<dim3(HID / 64, T_STEPS / 64), 256, 0, stream>>>(
        R2, w0, b0, R1, T_STEPS, HID, HID);
    sgemm_bias<1><<<dim3(HID / 64, T_STEPS / 64), 256, 0, stream>>>(
        R1, w1, b1, R2, T_STEPS, HID, HID);
    sgemm_bias<0><<<dim3(1, T_STEPS / 64), 256, 0, stream>>>(
        R2, w2, b2, out, T_STEPS, 49, 2048);
}